// Round 1
// baseline (6160.803 us; speedup 1.0000x reference)
//
#include <hip/hip_runtime.h>
#include <hip/hip_bf16.h>

#define BATCH 4
#define TLEN 8192
#define RES_CH 64
#define DIL_CH 128
#define SKIP_CH 128
#define COND_DIM 80
#define NLAYER 20
#define TT 64   // t-tile per block

// One layer of the WaveNet stack.
// Block: 256 threads = 4 waves. lt = t within tile (0..63), wv = wave (0..3).
// Wave wv computes h rows [wv*16, wv*16+16) (tanh half) and +64 (sigmoid half),
// so gating is wave-local. Then all waves stride over the 192 res+skip rows.
__global__ __launch_bounds__(256, 2) void wavenet_layer(
    const float* __restrict__ xs_in, float* __restrict__ xs_out,
    const float* __restrict__ cond, float* __restrict__ out,
    const float* __restrict__ conv_w, const float* __restrict__ conv_b,
    const float* __restrict__ cond_w, const float* __restrict__ cond_b,
    const float* __restrict__ res_w, const float* __restrict__ res_b,
    const float* __restrict__ skip_w, const float* __restrict__ skip_b,
    int layer, int dil, int first)
{
    __shared__ float s_cur[RES_CH][TT];   // xs[:, t]
    __shared__ float s_shf[RES_CH][TT];   // xs[:, t-d] (0 if t-d<0)
    __shared__ float s_cnd[COND_DIM][TT];
    __shared__ float s_z[RES_CH][TT];

    const int b  = blockIdx.y;
    const int t0 = blockIdx.x * TT;
    const int tid = threadIdx.x;
    const int lt = tid & 63;
    const int wv = tid >> 6;

    // ---- stage activations ----
    for (int idx = tid; idx < RES_CH * TT; idx += 256) {
        int r = idx >> 6, c = idx & 63;
        s_cur[r][c] = xs_in[(b * RES_CH + r) * TLEN + t0 + c];
        int ts = t0 + c - dil;
        s_shf[r][c] = (ts >= 0) ? xs_in[(b * RES_CH + r) * TLEN + ts] : 0.0f;
    }
    for (int idx = tid; idx < COND_DIM * TT; idx += 256) {
        int r = idx >> 6, c = idx & 63;
        s_cnd[r][c] = cond[(b * COND_DIM + r) * TLEN + t0 + c];
    }
    __syncthreads();

    // ---- h = conv + cond projection, 16 tanh rows + 16 sigmoid rows per wave ----
    const int ot0 = wv * 16;
    float ht[16], hs[16];
    #pragma unroll
    for (int j = 0; j < 16; ++j) {
        ht[j] = conv_b[layer * DIL_CH + ot0 + j] + cond_b[layer * DIL_CH + ot0 + j];
        hs[j] = conv_b[layer * DIL_CH + 64 + ot0 + j] + cond_b[layer * DIL_CH + 64 + ot0 + j];
    }
    const float* cw = conv_w + (size_t)layer * DIL_CH * RES_CH * 2;
    #pragma unroll 4
    for (int k = 0; k < RES_CH; ++k) {
        float xc = s_cur[k][lt];
        float xf = s_shf[k][lt];
        #pragma unroll
        for (int j = 0; j < 16; ++j) {
            const float* wt = cw + ((ot0 + j) * RES_CH + k) * 2;
            const float* ws = cw + ((ot0 + j + 64) * RES_CH + k) * 2;
            ht[j] += wt[0] * xf + wt[1] * xc;   // f=0 -> t-d tap, f=1 -> t tap
            hs[j] += ws[0] * xf + ws[1] * xc;
        }
    }
    const float* cdw = cond_w + (size_t)layer * DIL_CH * COND_DIM;
    #pragma unroll 4
    for (int c = 0; c < COND_DIM; ++c) {
        float xc = s_cnd[c][lt];
        #pragma unroll
        for (int j = 0; j < 16; ++j) {
            ht[j] += cdw[(ot0 + j) * COND_DIM + c] * xc;
            hs[j] += cdw[(ot0 + j + 64) * COND_DIM + c] * xc;
        }
    }
    #pragma unroll
    for (int j = 0; j < 16; ++j) {
        float zt = tanhf(ht[j]);
        float zs = 1.0f / (1.0f + __expf(-hs[j]));
        s_z[ot0 + j][lt] = zt * zs;
    }
    __syncthreads();

    // ---- res (rows 0..63 -> xs_out) and skip (rows 64..191 -> out accum) ----
    // Each wave owns rows r = wv + 4*m, m = 0..47, processed in 6 chunks of 8
    // so z LDS reads amortize over 8 FMAs.
    for (int mc = 0; mc < 6; ++mc) {
        float acc[8];
        const float* wrow[8];
        int rr[8];
        #pragma unroll
        for (int q = 0; q < 8; ++q) {
            int r = wv + 4 * (mc * 8 + q);
            rr[q] = r;
            if (r < 64) {
                acc[q] = res_b[layer * RES_CH + r];
                wrow[q] = res_w + ((size_t)layer * RES_CH + r) * 64;
            } else {
                acc[q] = skip_b[layer * SKIP_CH + (r - 64)];
                wrow[q] = skip_w + ((size_t)layer * SKIP_CH + (r - 64)) * 64;
            }
        }
        #pragma unroll 4
        for (int k = 0; k < 64; ++k) {
            float zk = s_z[k][lt];
            #pragma unroll
            for (int q = 0; q < 8; ++q) acc[q] += wrow[q][k] * zk;
        }
        #pragma unroll
        for (int q = 0; q < 8; ++q) {
            int r = rr[q];
            int t = t0 + lt;
            if (r < 64) {
                xs_out[(b * RES_CH + r) * TLEN + t] = acc[q] + s_cur[r][lt];
            } else {
                float* o = out + (b * SKIP_CH + (r - 64)) * TLEN + t;
                *o = first ? acc[q] : (*o + acc[q]);
            }
        }
    }
}

extern "C" void kernel_launch(void* const* d_in, const int* in_sizes, int n_in,
                              void* d_out, int out_size, void* d_ws, size_t ws_size,
                              hipStream_t stream) {
    const float* x      = (const float*)d_in[0];
    const float* cond   = (const float*)d_in[1];
    const float* conv_w = (const float*)d_in[2];
    const float* conv_b = (const float*)d_in[3];
    const float* cond_w = (const float*)d_in[4];
    const float* cond_b = (const float*)d_in[5];
    const float* res_w  = (const float*)d_in[6];
    const float* res_b  = (const float*)d_in[7];
    const float* skip_w = (const float*)d_in[8];
    const float* skip_b = (const float*)d_in[9];
    float* out = (float*)d_out;

    float* xsA = (float*)d_ws;
    float* xsB = xsA + (size_t)BATCH * RES_CH * TLEN;

    hipMemcpyAsync(xsA, x, (size_t)BATCH * RES_CH * TLEN * sizeof(float),
                   hipMemcpyDeviceToDevice, stream);

    static const int dil[NLAYER] = {1, 2, 4, 8, 16, 32, 64, 128, 256, 512,
                                    1, 2, 4, 8, 16, 32, 64, 128, 256, 512};

    dim3 grid(TLEN / TT, BATCH);
    dim3 block(256);
    const float* cur = xsA;
    float* nxt = xsB;
    for (int i = 0; i < NLAYER; ++i) {
        wavenet_layer<<<grid, block, 0, stream>>>(
            cur, nxt, cond, out,
            conv_w, conv_b, cond_w, cond_b, res_w, res_b, skip_w, skip_b,
            i, dil[i], (i == 0) ? 1 : 0);
        const float* tmp = nxt;
        nxt = (float*)cur;
        cur = tmp;
    }
}

// Round 2
// 4546.647 us; speedup vs baseline: 1.3550x; 1.3550x over previous
//
#include <hip/hip_runtime.h>
#include <hip/hip_bf16.h>

#define BATCH 4
#define TLEN 8192
#define RES_CH 64
#define DIL_CH 128
#define SKIP_CH 128
#define COND_DIM 80
#define NLAYER 20
#define TT 64   // t-tile per block

// One layer of the WaveNet stack.
// Block: 256 threads = 4 waves. lt = t within tile (0..63), wv = wave (0..3).
// wv is readfirstlane'd so ALL weight/bias addresses are wave-uniform ->
// scalar s_load_dwordx4 through the scalar cache (the R1 kernel emitted
// divergent global_load_dword per weight and was VMEM-latency-bound).
__global__ __launch_bounds__(256, 2) void wavenet_layer(
    const float* __restrict__ xs_in, float* __restrict__ xs_out,
    const float* __restrict__ cond, float* __restrict__ out,
    const float* __restrict__ conv_w, const float* __restrict__ conv_b,
    const float* __restrict__ cond_w, const float* __restrict__ cond_b,
    const float* __restrict__ res_w, const float* __restrict__ res_b,
    const float* __restrict__ skip_w, const float* __restrict__ skip_b,
    int layer, int dil, int first)
{
    __shared__ float s_cur[RES_CH][TT];   // xs[:, t]
    __shared__ float s_shf[RES_CH][TT];   // xs[:, t-d] (0 if t-d<0)
    __shared__ float s_cnd[COND_DIM][TT];
    __shared__ float s_z[RES_CH][TT];

    const int b  = blockIdx.y;
    const int t0 = blockIdx.x * TT;
    const int tid = threadIdx.x;
    const int lt = tid & 63;
    const int wv = __builtin_amdgcn_readfirstlane(tid >> 6);  // wave-uniform!

    // ---- stage activations ----
    for (int idx = tid; idx < RES_CH * TT; idx += 256) {
        int r = idx >> 6, c = idx & 63;
        s_cur[r][c] = xs_in[(b * RES_CH + r) * TLEN + t0 + c];
        int ts = t0 + c - dil;
        s_shf[r][c] = (ts >= 0) ? xs_in[(b * RES_CH + r) * TLEN + ts] : 0.0f;
    }
    for (int idx = tid; idx < COND_DIM * TT; idx += 256) {
        int r = idx >> 6, c = idx & 63;
        s_cnd[r][c] = cond[(b * COND_DIM + r) * TLEN + t0 + c];
    }
    __syncthreads();

    // ---- h = conv + cond projection, 16 tanh rows + 16 sigmoid rows per wave ----
    const int ot0 = wv * 16;
    float ht[16], hs[16];
    #pragma unroll
    for (int j = 0; j < 16; ++j) {
        ht[j] = conv_b[layer * DIL_CH + ot0 + j] + cond_b[layer * DIL_CH + ot0 + j];
        hs[j] = conv_b[layer * DIL_CH + 64 + ot0 + j] + cond_b[layer * DIL_CH + 64 + ot0 + j];
    }

    // conv: weights (o, k, f) with f=2 contiguous; float4 covers taps for k,k+1
    const float* cw = conv_w + (size_t)layer * DIL_CH * RES_CH * 2;
    #pragma unroll 4
    for (int k = 0; k < RES_CH; k += 2) {
        float xf0 = s_shf[k][lt],     xc0 = s_cur[k][lt];
        float xf1 = s_shf[k + 1][lt], xc1 = s_cur[k + 1][lt];
        #pragma unroll
        for (int j = 0; j < 16; ++j) {
            float4 wt = *(const float4*)(cw + ((ot0 + j) * RES_CH + k) * 2);
            float4 ws = *(const float4*)(cw + ((ot0 + j + 64) * RES_CH + k) * 2);
            ht[j] += wt.x * xf0 + wt.y * xc0 + wt.z * xf1 + wt.w * xc1;
            hs[j] += ws.x * xf0 + ws.y * xc0 + ws.z * xf1 + ws.w * xc1;
        }
    }

    // cond: weights (o, c), c contiguous; float4 over c
    const float* cdw = cond_w + (size_t)layer * DIL_CH * COND_DIM;
    #pragma unroll 2
    for (int c = 0; c < COND_DIM; c += 4) {
        float x0 = s_cnd[c][lt],     x1 = s_cnd[c + 1][lt];
        float x2 = s_cnd[c + 2][lt], x3 = s_cnd[c + 3][lt];
        #pragma unroll
        for (int j = 0; j < 16; ++j) {
            float4 wt = *(const float4*)(cdw + (ot0 + j) * COND_DIM + c);
            float4 ws = *(const float4*)(cdw + (ot0 + j + 64) * COND_DIM + c);
            ht[j] += wt.x * x0 + wt.y * x1 + wt.z * x2 + wt.w * x3;
            hs[j] += ws.x * x0 + ws.y * x1 + ws.z * x2 + ws.w * x3;
        }
    }

    #pragma unroll
    for (int j = 0; j < 16; ++j) {
        float zt = tanhf(ht[j]);
        float zs = 1.0f / (1.0f + __expf(-hs[j]));
        s_z[ot0 + j][lt] = zt * zs;
    }
    __syncthreads();

    // ---- res (rows 0..63 -> xs_out) and skip (rows 64..191 -> out accum) ----
    // Each wave owns rows r = wv + 4*m, m = 0..47, in 6 chunks of 8.
    for (int mc = 0; mc < 6; ++mc) {
        float acc[8];
        const float* wrow[8];
        int rr[8];
        #pragma unroll
        for (int q = 0; q < 8; ++q) {
            int r = wv + 4 * (mc * 8 + q);
            rr[q] = r;
            if (r < 64) {
                acc[q] = res_b[layer * RES_CH + r];
                wrow[q] = res_w + ((size_t)layer * RES_CH + r) * 64;
            } else {
                acc[q] = skip_b[layer * SKIP_CH + (r - 64)];
                wrow[q] = skip_w + ((size_t)layer * SKIP_CH + (r - 64)) * 64;
            }
        }
        #pragma unroll 2
        for (int k = 0; k < 64; k += 4) {
            float z0 = s_z[k][lt],     z1 = s_z[k + 1][lt];
            float z2 = s_z[k + 2][lt], z3 = s_z[k + 3][lt];
            #pragma unroll
            for (int q = 0; q < 8; ++q) {
                float4 w = *(const float4*)(wrow[q] + k);
                acc[q] += w.x * z0 + w.y * z1 + w.z * z2 + w.w * z3;
            }
        }
        #pragma unroll
        for (int q = 0; q < 8; ++q) {
            int r = rr[q];
            int t = t0 + lt;
            if (r < 64) {
                xs_out[(b * RES_CH + r) * TLEN + t] = acc[q] + s_cur[r][lt];
            } else {
                float* o = out + (b * SKIP_CH + (r - 64)) * TLEN + t;
                *o = first ? acc[q] : (*o + acc[q]);
            }
        }
    }
}

extern "C" void kernel_launch(void* const* d_in, const int* in_sizes, int n_in,
                              void* d_out, int out_size, void* d_ws, size_t ws_size,
                              hipStream_t stream) {
    const float* x      = (const float*)d_in[0];
    const float* cond   = (const float*)d_in[1];
    const float* conv_w = (const float*)d_in[2];
    const float* conv_b = (const float*)d_in[3];
    const float* cond_w = (const float*)d_in[4];
    const float* cond_b = (const float*)d_in[5];
    const float* res_w  = (const float*)d_in[6];
    const float* res_b  = (const float*)d_in[7];
    const float* skip_w = (const float*)d_in[8];
    const float* skip_b = (const float*)d_in[9];
    float* out = (float*)d_out;

    float* xsA = (float*)d_ws;
    float* xsB = xsA + (size_t)BATCH * RES_CH * TLEN;

    hipMemcpyAsync(xsA, x, (size_t)BATCH * RES_CH * TLEN * sizeof(float),
                   hipMemcpyDeviceToDevice, stream);

    static const int dil[NLAYER] = {1, 2, 4, 8, 16, 32, 64, 128, 256, 512,
                                    1, 2, 4, 8, 16, 32, 64, 128, 256, 512};

    dim3 grid(TLEN / TT, BATCH);
    dim3 block(256);
    const float* cur = xsA;
    float* nxt = xsB;
    for (int i = 0; i < NLAYER; ++i) {
        wavenet_layer<<<grid, block, 0, stream>>>(
            cur, nxt, cond, out,
            conv_w, conv_b, cond_w, cond_b, res_w, res_b, skip_w, skip_b,
            i, dil[i], (i == 0) ? 1 : 0);
        const float* tmp = nxt;
        nxt = (float*)cur;
        cur = tmp;
    }
}

// Round 3
// 567.796 us; speedup vs baseline: 10.8504x; 8.0075x over previous
//
#include <hip/hip_runtime.h>

#define BATCH 4
#define TLEN 8192
#define RES_CH 64
#define DIL_CH 128
#define SKIP_CH 128
#define COND_DIM 80
#define NLAYER 20
#define NTILE 128          // TLEN/64 real tiles
#define GUARD 8            // zero guard tiles (max dil 512 = 8*64)
#define ATILE (NTILE + GUARD)

typedef __attribute__((ext_vector_type(8))) short bf16x8;
typedef __attribute__((ext_vector_type(8))) unsigned short u16x8;
typedef __attribute__((ext_vector_type(4))) float f32x4;

__device__ __forceinline__ unsigned short f2b(float f) {
    unsigned u = __float_as_uint(f);
    return (unsigned short)((u + 0x7fffu + ((u >> 16) & 1u)) >> 16);  // RNE
}

// ---------------- prep: weights -> fragment-ordered bf16 ----------------
// W1F[layer][ks(7)][mfslot(8)][lane(64)][j(8)]  (K order: x-shift 0-63, x-cur 64-127, cond 128-207, pad)
// W2F[layer][ks(2)][mfslot(12)][lane(64)][j(8)] (rows: res 0-63, skip 64-191)
__global__ void prep_w(const float* __restrict__ conv_w, const float* __restrict__ conv_b,
                       const float* __restrict__ cond_w, const float* __restrict__ cond_b,
                       const float* __restrict__ res_w,  const float* __restrict__ res_b,
                       const float* __restrict__ skip_w, const float* __restrict__ skip_b,
                       unsigned short* __restrict__ w1f, unsigned short* __restrict__ w2f,
                       float* __restrict__ hb, float* __restrict__ rsb) {
    const int layer = blockIdx.x, tid = threadIdx.x;
    for (int idx = tid; idx < 7 * 8 * 512; idx += 256) {
        int ks = idx >> 12;
        int lane = (idx >> 3) & 63;
        int j = idx & 7;
        int mf = (idx >> 9) & 7;
        int m = mf * 16 + (lane & 15);
        int k = ks * 32 + ((lane >> 4) << 3) + j;
        float v;
        if (k < 64)       v = conv_w[(((size_t)layer * 128 + m) * 64 + k) * 2 + 0];
        else if (k < 128) v = conv_w[(((size_t)layer * 128 + m) * 64 + (k - 64)) * 2 + 1];
        else if (k < 208) v = cond_w[((size_t)layer * 128 + m) * 80 + (k - 128)];
        else              v = 0.0f;
        w1f[(size_t)layer * 7 * 8 * 512 + idx] = f2b(v);
    }
    for (int idx = tid; idx < 2 * 12 * 512; idx += 256) {
        int ks = idx / (12 * 512);
        int rem = idx - ks * 12 * 512;
        int mf = rem >> 9;
        int lane = (rem >> 3) & 63;
        int j = rem & 7;
        int m = mf * 16 + (lane & 15);
        int k = ks * 32 + ((lane >> 4) << 3) + j;
        float v = (m < 64) ? res_w[((size_t)layer * 64 + m) * 64 + k]
                           : skip_w[((size_t)layer * 128 + (m - 64)) * 64 + k];
        w2f[(size_t)layer * 2 * 12 * 512 + idx] = f2b(v);
    }
    if (tid < 128) hb[layer * 128 + tid] = conv_b[layer * 128 + tid] + cond_b[layer * 128 + tid];
    if (tid < 192) rsb[layer * 192 + tid] =
        (tid < 64) ? res_b[layer * 64 + tid] : skip_b[layer * 128 + (tid - 64)];
}

// ---------------- prep: cond -> bf16 cells [b][tile][cg(12)][n(64)][8] ----------------
__global__ void prep_cond(const float* __restrict__ cond, unsigned short* __restrict__ condc) {
    __shared__ float ct[80][64];
    const int tile = blockIdx.x, b = blockIdx.y, tid = threadIdx.x;
    for (int idx = tid; idx < 80 * 64; idx += 256) {
        int ch = idx >> 6, n = idx & 63;
        ct[ch][n] = cond[((size_t)b * 80 + ch) * TLEN + tile * 64 + n];
    }
    __syncthreads();
    for (int idx = tid; idx < 12 * 64; idx += 256) {
        int cg = idx >> 6, n = idx & 63;
        u16x8 cell;
        #pragma unroll
        for (int j = 0; j < 8; ++j) {
            int ch = cg * 8 + j;
            cell[j] = (ch < 80) ? f2b(ct[ch][n]) : (unsigned short)0;
        }
        *(u16x8*)(condc + (((size_t)(b * NTILE + tile) * 12 + cg) * 64 + n) * 8) = cell;
    }
}

// ---------------- prep: x -> fp32 cells [b][atile(136)][cg(8)][n(64)][8] + zero guards ----------------
__global__ void prep_x(const float* __restrict__ x, float* __restrict__ xsA, float* __restrict__ xsB) {
    const int tile = blockIdx.x, b = blockIdx.y, tid = threadIdx.x;
    size_t base = ((size_t)b * ATILE + tile) * 8 * 64 * 8;
    if (tile < GUARD) {
        for (int idx = tid * 4; idx < 4096; idx += 1024) {
            float4 z = {0.f, 0.f, 0.f, 0.f};
            *(float4*)(xsA + base + idx) = z;
            *(float4*)(xsB + base + idx) = z;
        }
        return;
    }
    __shared__ float xt[64][64];
    const int rt = tile - GUARD;
    for (int idx = tid; idx < 64 * 64; idx += 256) {
        int ch = idx >> 6, n = idx & 63;
        xt[ch][n] = x[((size_t)b * 64 + ch) * TLEN + rt * 64 + n];
    }
    __syncthreads();
    for (int idx = tid; idx < 8 * 64; idx += 256) {
        int cg = idx >> 6, n = idx & 63;
        float4 v0, v1;
        v0.x = xt[cg * 8 + 0][n]; v0.y = xt[cg * 8 + 1][n];
        v0.z = xt[cg * 8 + 2][n]; v0.w = xt[cg * 8 + 3][n];
        v1.x = xt[cg * 8 + 4][n]; v1.y = xt[cg * 8 + 5][n];
        v1.z = xt[cg * 8 + 6][n]; v1.w = xt[cg * 8 + 7][n];
        float* dst = xsA + base + ((size_t)cg * 64 + n) * 8;
        *(float4*)dst = v0;
        *(float4*)(dst + 4) = v1;
    }
}

// ---------------- per-layer MFMA kernel ----------------
// 4 waves. GEMM1: H[128 x 64] = W1[128 x 224] * act[224 x 64], wave w rows [32w,32w+32).
// Gate via LDS. GEMM2: [res;skip][192 x 64] = W2 * z[64 x 64], wave w rows [48w,48w+48).
__global__ __launch_bounds__(256, 2) void wavenet_mfma(
    const float* __restrict__ xin, float* __restrict__ xout,
    const unsigned short* __restrict__ condc, float* __restrict__ out,
    const unsigned short* __restrict__ w1f, const unsigned short* __restrict__ w2f,
    const float* __restrict__ hb, const float* __restrict__ rsb,
    int layer, int dil, int first) {
    __shared__ float H[128][67];           // padded: conflict-light frag writes
    __shared__ unsigned short zc[8 * 64 * 8];  // z cells [cg(8)][n(64)][j(8)]

    const int b = blockIdx.y, tile = blockIdx.x, t0 = tile * 64;
    const int tid = threadIdx.x;
    const int lane = tid & 63;
    const int wv = __builtin_amdgcn_readfirstlane(tid >> 6);
    const int ln = lane & 15, lg = lane >> 4;

    const float* xb = xin + (size_t)b * ATILE * 8 * 64 * 8;

    // ---- GEMM1 ----
    f32x4 acc[2][4];
    #pragma unroll
    for (int mf = 0; mf < 2; ++mf)
        #pragma unroll
        for (int nf = 0; nf < 4; ++nf) acc[mf][nf] = (f32x4){0.f, 0.f, 0.f, 0.f};

    const unsigned short* w1l = w1f + (size_t)layer * 7 * 8 * 512;

    #pragma unroll
    for (int ks = 0; ks < 7; ++ks) {
        bf16x8 af0 = *(const bf16x8*)(w1l + (size_t)(ks * 8 + wv * 2 + 0) * 512 + lane * 8);
        bf16x8 af1 = *(const bf16x8*)(w1l + (size_t)(ks * 8 + wv * 2 + 1) * 512 + lane * 8);
        bf16x8 bfr[4];
        if (ks < 4) {
            const int shift = (ks < 2) ? dil : 0;
            const int cg = (ks & 1) * 4 + lg;
            #pragma unroll
            for (int nf = 0; nf < 4; ++nf) {
                int u = t0 + nf * 16 + ln - shift + GUARD * 64;  // >= 0 always
                const float* p = xb + (((size_t)(u >> 6) * 8 + cg) * 64 + (u & 63)) * 8;
                float4 f0 = *(const float4*)p;
                float4 f1 = *(const float4*)(p + 4);
                bf16x8 t;
                t[0] = f2b(f0.x); t[1] = f2b(f0.y); t[2] = f2b(f0.z); t[3] = f2b(f0.w);
                t[4] = f2b(f1.x); t[5] = f2b(f1.y); t[6] = f2b(f1.z); t[7] = f2b(f1.w);
                bfr[nf] = t;
            }
        } else {
            const int cg = (ks - 4) * 4 + lg;
            const unsigned short* cb = condc + (((size_t)(b * NTILE + tile) * 12 + cg) * 64) * 8;
            #pragma unroll
            for (int nf = 0; nf < 4; ++nf)
                bfr[nf] = *(const bf16x8*)(cb + (nf * 16 + ln) * 8);
        }
        #pragma unroll
        for (int mf = 0; mf < 2; ++mf)
            #pragma unroll
            for (int nf = 0; nf < 4; ++nf)
                acc[mf][nf] = __builtin_amdgcn_mfma_f32_16x16x32_bf16(
                    (mf == 0) ? af0 : af1, bfr[nf], acc[mf][nf], 0, 0, 0);
    }

    // write H (+ fused conv/cond bias). C layout: n = ln, m_local = 4*lg + reg.
    const float* hbl = hb + layer * 128;
    #pragma unroll
    for (int mf = 0; mf < 2; ++mf)
        #pragma unroll
        for (int nf = 0; nf < 4; ++nf)
            #pragma unroll
            for (int r = 0; r < 4; ++r) {
                int m = wv * 32 + mf * 16 + lg * 4 + r;
                H[m][nf * 16 + ln] = acc[mf][nf][r] + hbl[m];
            }
    __syncthreads();

    // ---- gate: z = tanh(H_top) * sigmoid(H_bot), write bf16 cells ----
    {
        const int n = tid & 63, r0 = (tid >> 6) * 16;
        #pragma unroll
        for (int i = 0; i < 8; ++i) {
            int r = r0 + 2 * i;
            float z0 = tanhf(H[r][n])     * (1.0f / (1.0f + __expf(-H[r + 64][n])));
            float z1 = tanhf(H[r + 1][n]) * (1.0f / (1.0f + __expf(-H[r + 65][n])));
            unsigned pack = (unsigned)f2b(z0) | ((unsigned)f2b(z1) << 16);
            *(unsigned*)(&zc[((r >> 3) * 64 + n) * 8 + (r & 7)]) = pack;
        }
    }
    __syncthreads();

    // ---- GEMM2 ----
    f32x4 acc2[3][4];
    #pragma unroll
    for (int mf = 0; mf < 3; ++mf)
        #pragma unroll
        for (int nf = 0; nf < 4; ++nf) acc2[mf][nf] = (f32x4){0.f, 0.f, 0.f, 0.f};

    const unsigned short* w2l = w2f + (size_t)layer * 2 * 12 * 512;
    #pragma unroll
    for (int ks = 0; ks < 2; ++ks) {
        bf16x8 a2[3];
        #pragma unroll
        for (int mf = 0; mf < 3; ++mf)
            a2[mf] = *(const bf16x8*)(w2l + (size_t)(ks * 12 + wv * 3 + mf) * 512 + lane * 8);
        bf16x8 b2[4];
        #pragma unroll
        for (int nf = 0; nf < 4; ++nf)
            b2[nf] = *(const bf16x8*)(&zc[(((ks * 4 + lg) * 64) + nf * 16 + ln) * 8]);
        #pragma unroll
        for (int mf = 0; mf < 3; ++mf)
            #pragma unroll
            for (int nf = 0; nf < 4; ++nf)
                acc2[mf][nf] = __builtin_amdgcn_mfma_f32_16x16x32_bf16(a2[mf], b2[nf], acc2[mf][nf], 0, 0, 0);
    }

    // ---- epilogue ----
    const float* rsl = rsb + layer * 192;
    #pragma unroll
    for (int mf = 0; mf < 3; ++mf) {
        const int mrow = wv * 48 + mf * 16;  // uniform per (wave, mf)
        if (mrow < 64) {
            // res rows: stage (bias + gemm) into H for cell repack
            #pragma unroll
            for (int nf = 0; nf < 4; ++nf)
                #pragma unroll
                for (int r = 0; r < 4; ++r) {
                    int m = mrow + lg * 4 + r;
                    H[m][nf * 16 + ln] = acc2[mf][nf][r] + rsl[m];
                }
        } else {
            // skip rows: accumulate into out
            #pragma unroll
            for (int nf = 0; nf < 4; ++nf)
                #pragma unroll
                for (int r = 0; r < 4; ++r) {
                    int m = mrow + lg * 4 + r;
                    float v = acc2[mf][nf][r] + rsl[m];
                    float* o = out + ((size_t)(b * 128 + (m - 64))) * TLEN + t0 + nf * 16 + ln;
                    *o = first ? v : (*o + v);
                }
        }
    }
    __syncthreads();

    // ---- repack res rows -> xs_out cells, adding fp32 residual (coalesced) ----
    {
        float* xob = xout + (size_t)b * ATILE * 8 * 64 * 8;
        const int n = tid & 63;
        #pragma unroll
        for (int c2 = 0; c2 < 2; ++c2) {
            int cg = (tid >> 6) * 2 + c2;
            size_t cell = (((size_t)(tile + GUARD) * 8 + cg) * 64 + n) * 8;
            float4 o0 = *(const float4*)(xb + cell);
            float4 o1 = *(const float4*)(xb + cell + 4);
            o0.x += H[cg * 8 + 0][n]; o0.y += H[cg * 8 + 1][n];
            o0.z += H[cg * 8 + 2][n]; o0.w += H[cg * 8 + 3][n];
            o1.x += H[cg * 8 + 4][n]; o1.y += H[cg * 8 + 5][n];
            o1.z += H[cg * 8 + 6][n]; o1.w += H[cg * 8 + 7][n];
            *(float4*)(xob + cell) = o0;
            *(float4*)(xob + cell + 4) = o1;
        }
    }
}

extern "C" void kernel_launch(void* const* d_in, const int* in_sizes, int n_in,
                              void* d_out, int out_size, void* d_ws, size_t ws_size,
                              hipStream_t stream) {
    const float* x      = (const float*)d_in[0];
    const float* cond   = (const float*)d_in[1];
    const float* conv_w = (const float*)d_in[2];
    const float* conv_b = (const float*)d_in[3];
    const float* cond_w = (const float*)d_in[4];
    const float* cond_b = (const float*)d_in[5];
    const float* res_w  = (const float*)d_in[6];
    const float* res_b  = (const float*)d_in[7];
    const float* skip_w = (const float*)d_in[8];
    const float* skip_b = (const float*)d_in[9];
    float* out = (float*)d_out;

    // ws layout (bytes)
    char* ws = (char*)d_ws;
    const size_t XS_BYTES = (size_t)BATCH * ATILE * 8 * 64 * 8 * 4;      // 8,912,896
    float* xsA = (float*)(ws);
    float* xsB = (float*)(ws + XS_BYTES);
    unsigned short* condc = (unsigned short*)(ws + 2 * XS_BYTES);
    const size_t COND_BYTES = (size_t)BATCH * NTILE * 12 * 64 * 8 * 2;   // 6,291,456
    unsigned short* w1f = (unsigned short*)(ws + 2 * XS_BYTES + COND_BYTES);
    const size_t W1_BYTES = (size_t)NLAYER * 7 * 8 * 512 * 2;            // 1,146,880
    unsigned short* w2f = (unsigned short*)(ws + 2 * XS_BYTES + COND_BYTES + W1_BYTES);
    const size_t W2_BYTES = (size_t)NLAYER * 2 * 12 * 512 * 2;           // 491,520
    float* hb  = (float*)(ws + 2 * XS_BYTES + COND_BYTES + W1_BYTES + W2_BYTES);
    float* rsb = hb + NLAYER * 128;

    prep_w<<<NLAYER, 256, 0, stream>>>(conv_w, conv_b, cond_w, cond_b,
                                       res_w, res_b, skip_w, skip_b, w1f, w2f, hb, rsb);
    prep_cond<<<dim3(NTILE, BATCH), 256, 0, stream>>>(cond, condc);
    prep_x<<<dim3(ATILE, BATCH), 256, 0, stream>>>(x, xsA, xsB);

    static const int dil[NLAYER] = {1, 2, 4, 8, 16, 32, 64, 128, 256, 512,
                                    1, 2, 4, 8, 16, 32, 64, 128, 256, 512};

    const float* cur = xsA;
    float* nxt = xsB;
    for (int i = 0; i < NLAYER; ++i) {
        wavenet_mfma<<<dim3(NTILE, BATCH), 256, 0, stream>>>(
            cur, nxt, condc, out, w1f, w2f, hb, rsb, i, dil[i], (i == 0) ? 1 : 0);
        const float* tmp = nxt;
        nxt = (float*)cur;
        cur = tmp;
    }
}

// Round 4
// 275.495 us; speedup vs baseline: 22.3627x; 2.0610x over previous
//
#include <hip/hip_runtime.h>

#define BATCH 4
#define TLEN 8192
#define NLAYER 20
#define NTILE 128          // TLEN/64 real tiles
#define GUARD 8            // zero guard tiles (max dil 512 = 8*64)
#define ATILE (NTILE + GUARD)
#define CELL 4096          // 8 cg * 64 n * 8 j elements per (b,tile)

typedef __attribute__((ext_vector_type(8))) short bf16x8;
typedef __attribute__((ext_vector_type(8))) unsigned short u16x8;
typedef __attribute__((ext_vector_type(4))) short s16x4;
typedef __attribute__((ext_vector_type(4))) float f32x4;

__device__ __forceinline__ unsigned short f2b(float f) {
    unsigned u = __float_as_uint(f);
    return (unsigned short)((u + 0x7fffu + ((u >> 16) & 1u)) >> 16);  // RNE
}

// ---------------- prep: weights -> fragment-ordered bf16 ----------------
// w1f[l][ks7][slot8][lane64][j8]   K: x-shift 0-63 | x-cur 64-127 | cond 128-207 | pad
// w2f[l][ks2][slot4][lane64][j8]   res rows 0-63
// wsf[l*2+ks][slot8][lane64][j8]   skip rows, K-concat over layers (final GEMM)
__global__ void prep_w(const float* __restrict__ conv_w, const float* __restrict__ conv_b,
                       const float* __restrict__ cond_w, const float* __restrict__ cond_b,
                       const float* __restrict__ res_w,  const float* __restrict__ res_b,
                       const float* __restrict__ skip_w, const float* __restrict__ skip_b,
                       unsigned short* __restrict__ w1f, unsigned short* __restrict__ w2f,
                       unsigned short* __restrict__ wsf,
                       float* __restrict__ hb, float* __restrict__ rb, float* __restrict__ sbt) {
    const int l = blockIdx.x, tid = threadIdx.x;
    const int start = blockIdx.y * 256 + tid;
    for (int idx = start; idx < 7 * 8 * 512; idx += 2048) {
        int ks = idx >> 12;
        int lane = (idx >> 3) & 63, j = idx & 7, mf = (idx >> 9) & 7;
        int m = mf * 16 + (lane & 15);
        int k = ks * 32 + ((lane >> 4) << 3) + j;
        float v;
        if (k < 64)       v = conv_w[(((size_t)l * 128 + m) * 64 + k) * 2 + 0];
        else if (k < 128) v = conv_w[(((size_t)l * 128 + m) * 64 + (k - 64)) * 2 + 1];
        else if (k < 208) v = cond_w[((size_t)l * 128 + m) * 80 + (k - 128)];
        else              v = 0.0f;
        w1f[(size_t)l * 7 * 8 * 512 + idx] = f2b(v);
    }
    for (int idx = start; idx < 2 * 4 * 512; idx += 2048) {
        int ks = idx >> 11;
        int slot = (idx >> 9) & 3, lane = (idx >> 3) & 63, j = idx & 7;
        int m = slot * 16 + (lane & 15);
        int k = ks * 32 + ((lane >> 4) << 3) + j;
        w2f[(size_t)l * 2 * 4 * 512 + idx] = f2b(res_w[((size_t)l * 64 + m) * 64 + k]);
    }
    for (int idx = start; idx < 2 * 8 * 512; idx += 2048) {
        int ks = idx >> 12;
        int slot = (idx >> 9) & 7, lane = (idx >> 3) & 63, j = idx & 7;
        int m = slot * 16 + (lane & 15);
        int k = ks * 32 + ((lane >> 4) << 3) + j;
        wsf[((size_t)(l * 2 + ks) * 8 + slot) * 512 + lane * 8 + j] =
            f2b(skip_w[((size_t)l * 128 + m) * 64 + k]);
    }
    if (blockIdx.y == 0) {
        if (tid < 128) hb[l * 128 + tid] = conv_b[l * 128 + tid] + cond_b[l * 128 + tid];
        if (tid < 64)  rb[l * 64 + tid] = res_b[l * 64 + tid];
        if (l == 0 && tid < 128) {
            float s = 0.f;
            for (int q = 0; q < NLAYER; ++q) s += skip_b[q * 128 + tid];
            sbt[tid] = s;
        }
    }
}

// ---------------- prep: cond -> bf16 cells [b][tile][cg12][n64][8] ----------------
__global__ void prep_cond(const float* __restrict__ cond, unsigned short* __restrict__ condc) {
    __shared__ float ct[80][64];
    const int tile = blockIdx.x, b = blockIdx.y, tid = threadIdx.x;
    for (int idx = tid; idx < 80 * 64; idx += 256) {
        int ch = idx >> 6, n = idx & 63;
        ct[ch][n] = cond[((size_t)b * 80 + ch) * TLEN + tile * 64 + n];
    }
    __syncthreads();
    for (int idx = tid; idx < 12 * 64; idx += 256) {
        int cg = idx >> 6, n = idx & 63;
        u16x8 cell;
        #pragma unroll
        for (int j = 0; j < 8; ++j) {
            int ch = cg * 8 + j;
            cell[j] = (ch < 80) ? f2b(ct[ch][n]) : (unsigned short)0;
        }
        *(u16x8*)(condc + (((size_t)(b * NTILE + tile) * 12 + cg) * 64 + n) * 8) = cell;
    }
}

// ---------------- prep: x -> fp32 + bf16 cells, zero guards of all buffers ----------------
__global__ void prep_x(const float* __restrict__ x,
                       float* __restrict__ xsA, float* __restrict__ xsB,
                       unsigned short* __restrict__ xbfA, unsigned short* __restrict__ xbfB) {
    const int tile = blockIdx.x, b = blockIdx.y, tid = threadIdx.x;
    size_t base = ((size_t)b * ATILE + tile) * CELL;
    if (tile < GUARD) {
        for (int idx = tid * 4; idx < CELL; idx += 1024) {
            float4 z = {0.f, 0.f, 0.f, 0.f};
            *(float4*)(xsA + base + idx) = z;
            *(float4*)(xsB + base + idx) = z;
            s16x4 zh = {0, 0, 0, 0};
            *(s16x4*)(xbfA + base + idx) = zh;
            *(s16x4*)(xbfB + base + idx) = zh;
        }
        return;
    }
    __shared__ float xt[64][64];
    const int rt = tile - GUARD;
    for (int idx = tid; idx < 64 * 64; idx += 256) {
        int ch = idx >> 6, n = idx & 63;
        xt[ch][n] = x[((size_t)b * 64 + ch) * TLEN + rt * 64 + n];
    }
    __syncthreads();
    for (int idx = tid; idx < 8 * 64; idx += 256) {
        int cg = idx >> 6, n = idx & 63;
        float* dst = xsA + base + ((size_t)cg * 64 + n) * 8;
        unsigned short* dbf = xbfA + base + ((size_t)cg * 64 + n) * 8;
        #pragma unroll
        for (int j = 0; j < 8; ++j) {
            float v = xt[cg * 8 + j][n];
            dst[j] = v;
            dbf[j] = f2b(v);
        }
    }
}

// ---------------- per-layer kernel ----------------
// GEMM1: H[128x64] = W1[128x224] @ [x(t-d);x(t);cond], gate -> z, GEMM2: res[64x64] += W2 @ z
__global__ __launch_bounds__(256, 2) void wavenet_mfma(
    const float* __restrict__ xin, float* __restrict__ xout,
    const unsigned short* __restrict__ xbf_in, unsigned short* __restrict__ xbf_out,
    const unsigned short* __restrict__ condc, unsigned short* __restrict__ zgs,
    const unsigned short* __restrict__ w1f, const unsigned short* __restrict__ w2f,
    const float* __restrict__ hb, const float* __restrict__ rb,
    int layer, int dil) {
    __shared__ float H[128][67];
    __shared__ unsigned short zc[8 * 64 * 8];

    const int b = blockIdx.y, tile = blockIdx.x, t0 = tile * 64;
    const int tid = threadIdx.x;
    const int lane = tid & 63;
    const int wv = __builtin_amdgcn_readfirstlane(tid >> 6);
    const int ln = lane & 15, lg = lane >> 4;

    const unsigned short* xbb = xbf_in + (size_t)b * ATILE * CELL;

    // ---- GEMM1 ----
    f32x4 acc[2][4];
    #pragma unroll
    for (int mf = 0; mf < 2; ++mf)
        #pragma unroll
        for (int nf = 0; nf < 4; ++nf) acc[mf][nf] = (f32x4){0.f, 0.f, 0.f, 0.f};

    const unsigned short* w1l = w1f + (size_t)layer * 7 * 8 * 512;

    #pragma unroll
    for (int ks = 0; ks < 7; ++ks) {
        bf16x8 af0 = *(const bf16x8*)(w1l + (size_t)(ks * 8 + wv * 2 + 0) * 512 + lane * 8);
        bf16x8 af1 = *(const bf16x8*)(w1l + (size_t)(ks * 8 + wv * 2 + 1) * 512 + lane * 8);
        bf16x8 bfr[4];
        if (ks < 4) {
            const int shift = (ks < 2) ? dil : 0;
            const int cg = (ks & 1) * 4 + lg;
            #pragma unroll
            for (int nf = 0; nf < 4; ++nf) {
                int u = t0 + nf * 16 + ln - shift + GUARD * 64;  // >= 0 always
                bfr[nf] = *(const bf16x8*)(xbb + (((size_t)(u >> 6) * 8 + cg) * 64 + (u & 63)) * 8);
            }
        } else {
            const int cg = (ks - 4) * 4 + lg;
            const unsigned short* cb = condc + (((size_t)(b * NTILE + tile) * 12 + cg) * 64) * 8;
            #pragma unroll
            for (int nf = 0; nf < 4; ++nf)
                bfr[nf] = *(const bf16x8*)(cb + (nf * 16 + ln) * 8);
        }
        #pragma unroll
        for (int mf = 0; mf < 2; ++mf)
            #pragma unroll
            for (int nf = 0; nf < 4; ++nf)
                acc[mf][nf] = __builtin_amdgcn_mfma_f32_16x16x32_bf16(
                    (mf == 0) ? af0 : af1, bfr[nf], acc[mf][nf], 0, 0, 0);
    }

    const float* hbl = hb + layer * 128;
    #pragma unroll
    for (int mf = 0; mf < 2; ++mf)
        #pragma unroll
        for (int nf = 0; nf < 4; ++nf)
            #pragma unroll
            for (int r = 0; r < 4; ++r) {
                int m = wv * 32 + mf * 16 + lg * 4 + r;
                H[m][nf * 16 + ln] = acc[mf][nf][r] + hbl[m];
            }
    __syncthreads();

    // ---- gate -> zc (bf16 cells) ----
    {
        const int n = tid & 63, r0 = (tid >> 6) * 16;
        #pragma unroll
        for (int i = 0; i < 8; ++i) {
            int r = r0 + 2 * i;
            float z0 = tanhf(H[r][n])     * (1.0f / (1.0f + __expf(-H[r + 64][n])));
            float z1 = tanhf(H[r + 1][n]) * (1.0f / (1.0f + __expf(-H[r + 65][n])));
            unsigned pack = (unsigned)f2b(z0) | ((unsigned)f2b(z1) << 16);
            *(unsigned*)(&zc[((r >> 3) * 64 + n) * 8 + (r & 7)]) = pack;
        }
    }
    __syncthreads();

    // ---- zc -> global z cells (for final skip GEMM), coalesced ----
    {
        unsigned short* zt = zgs + ((size_t)(b * NTILE) + tile) * CELL;
        for (int i = tid; i < 512; i += 256)
            *(u16x8*)(zt + i * 8) = *(const u16x8*)(&zc[i * 8]);
    }

    // ---- GEMM2 (res rows only) ----
    f32x4 acc2[4];
    #pragma unroll
    for (int nf = 0; nf < 4; ++nf) acc2[nf] = (f32x4){0.f, 0.f, 0.f, 0.f};
    const unsigned short* w2l = w2f + (size_t)layer * 2 * 4 * 512;
    #pragma unroll
    for (int ks = 0; ks < 2; ++ks) {
        bf16x8 a2 = *(const bf16x8*)(w2l + (size_t)(ks * 4 + wv) * 512 + lane * 8);
        #pragma unroll
        for (int nf = 0; nf < 4; ++nf) {
            bf16x8 b2 = *(const bf16x8*)(&zc[(((ks * 4 + lg) * 64) + nf * 16 + ln) * 8]);
            acc2[nf] = __builtin_amdgcn_mfma_f32_16x16x32_bf16(a2, b2, acc2[nf], 0, 0, 0);
        }
    }

    // ---- epilogue: residual add, write fp32 + bf16 cells directly ----
    {
        const float* xbt = xin + ((size_t)b * ATILE + tile + GUARD) * CELL;
        float* xot = xout + ((size_t)b * ATILE + tile + GUARD) * CELL;
        unsigned short* xobf = xbf_out + ((size_t)b * ATILE + tile + GUARD) * CELL;
        const float* rbl = rb + layer * 64;
        const int row0 = wv * 16 + lg * 4;
        float b0 = rbl[row0], b1 = rbl[row0 + 1], b2v = rbl[row0 + 2], b3 = rbl[row0 + 3];
        #pragma unroll
        for (int nf = 0; nf < 4; ++nf) {
            int n = nf * 16 + ln;
            size_t off = (((size_t)(row0 >> 3)) * 64 + n) * 8 + (row0 & 7);
            float4 old = *(const float4*)(xbt + off);
            float4 v;
            v.x = acc2[nf][0] + b0 + old.x;
            v.y = acc2[nf][1] + b1 + old.y;
            v.z = acc2[nf][2] + b2v + old.z;
            v.w = acc2[nf][3] + b3 + old.w;
            *(float4*)(xot + off) = v;
            s16x4 pk;
            pk.x = (short)f2b(v.x); pk.y = (short)f2b(v.y);
            pk.z = (short)f2b(v.z); pk.w = (short)f2b(v.w);
            *(s16x4*)(xobf + off) = pk;
        }
    }
}

// ---------------- final skip GEMM: out[128 x T] = Wskip[128 x 64G] @ Z ----------------
__global__ __launch_bounds__(256, 2) void skip_gemm(
    const unsigned short* __restrict__ zg, const unsigned short* __restrict__ wsf,
    const float* __restrict__ sbt, float* __restrict__ out,
    int nksl, int addbias, int accum) {
    const int b = blockIdx.y, tile = blockIdx.x;
    const int tid = threadIdx.x;
    const int lane = tid & 63;
    const int wv = __builtin_amdgcn_readfirstlane(tid >> 6);
    const int ln = lane & 15, lg = lane >> 4;

    f32x4 acc[2][4];
    #pragma unroll
    for (int mf = 0; mf < 2; ++mf)
        #pragma unroll
        for (int nf = 0; nf < 4; ++nf) acc[mf][nf] = (f32x4){0.f, 0.f, 0.f, 0.f};

    for (int ksl = 0; ksl < nksl; ++ksl) {
        const unsigned short* zt = zg + ((size_t)(ksl >> 1) * BATCH * NTILE + b * NTILE + tile) * CELL;
        const int cg = (ksl & 1) * 4 + lg;
        bf16x8 a0 = *(const bf16x8*)(wsf + ((size_t)ksl * 8 + wv * 2 + 0) * 512 + lane * 8);
        bf16x8 a1 = *(const bf16x8*)(wsf + ((size_t)ksl * 8 + wv * 2 + 1) * 512 + lane * 8);
        #pragma unroll
        for (int nf = 0; nf < 4; ++nf) {
            bf16x8 bfr = *(const bf16x8*)(zt + ((size_t)cg * 64 + nf * 16 + ln) * 8);
            acc[0][nf] = __builtin_amdgcn_mfma_f32_16x16x32_bf16(a0, bfr, acc[0][nf], 0, 0, 0);
            acc[1][nf] = __builtin_amdgcn_mfma_f32_16x16x32_bf16(a1, bfr, acc[1][nf], 0, 0, 0);
        }
    }

    #pragma unroll
    for (int mf = 0; mf < 2; ++mf)
        #pragma unroll
        for (int nf = 0; nf < 4; ++nf)
            #pragma unroll
            for (int r = 0; r < 4; ++r) {
                int m = (wv * 2 + mf) * 16 + lg * 4 + r;
                float v = acc[mf][nf][r] + (addbias ? sbt[m] : 0.0f);
                float* o = out + ((size_t)b * 128 + m) * TLEN + tile * 64 + nf * 16 + ln;
                *o = accum ? (*o + v) : v;
            }
}

extern "C" void kernel_launch(void* const* d_in, const int* in_sizes, int n_in,
                              void* d_out, int out_size, void* d_ws, size_t ws_size,
                              hipStream_t stream) {
    const float* x      = (const float*)d_in[0];
    const float* cond   = (const float*)d_in[1];
    const float* conv_w = (const float*)d_in[2];
    const float* conv_b = (const float*)d_in[3];
    const float* cond_w = (const float*)d_in[4];
    const float* cond_b = (const float*)d_in[5];
    const float* res_w  = (const float*)d_in[6];
    const float* res_b  = (const float*)d_in[7];
    const float* skip_w = (const float*)d_in[8];
    const float* skip_b = (const float*)d_in[9];
    float* out = (float*)d_out;

    char* ws = (char*)d_ws;
    const size_t XS   = (size_t)BATCH * ATILE * CELL * 4;   // 8,912,896
    const size_t XBF  = (size_t)BATCH * ATILE * CELL * 2;   // 4,456,448
    const size_t COND = (size_t)BATCH * NTILE * 12 * 512 * 2; // 6,291,456
    const size_t W1   = (size_t)NLAYER * 7 * 8 * 512 * 2;   // 1,146,880
    const size_t W2   = (size_t)NLAYER * 2 * 4 * 512 * 2;   //   163,840
    const size_t WSF  = (size_t)NLAYER * 2 * 8 * 512 * 2;   //   327,680
    const size_t HB   = NLAYER * 128 * 4;
    const size_t RB   = NLAYER * 64 * 4;
    const size_t SBT  = 128 * 4;
    const size_t ZL   = (size_t)BATCH * NTILE * CELL * 2;   // 4,194,304 per layer

    size_t off = 0;
    float* xsA = (float*)(ws + off); off += XS;
    float* xsB = (float*)(ws + off); off += XS;
    unsigned short* xbfA = (unsigned short*)(ws + off); off += XBF;
    unsigned short* xbfB = (unsigned short*)(ws + off); off += XBF;
    unsigned short* condc = (unsigned short*)(ws + off); off += COND;
    unsigned short* w1f = (unsigned short*)(ws + off); off += W1;
    unsigned short* w2f = (unsigned short*)(ws + off); off += W2;
    unsigned short* wsf = (unsigned short*)(ws + off); off += WSF;
    float* hb  = (float*)(ws + off); off += HB;
    float* rb  = (float*)(ws + off); off += RB;
    float* sbt = (float*)(ws + off); off += SBT;
    unsigned short* zg = (unsigned short*)(ws + off);
    size_t avail = (ws_size > off) ? (ws_size - off) : 0;
    int G = (int)(avail / ZL);
    if (G < 1) G = 1;           // ws too small would be fatal anyway
    if (G > NLAYER) G = NLAYER;

    prep_w<<<dim3(NLAYER, 8), 256, 0, stream>>>(conv_w, conv_b, cond_w, cond_b,
                                                res_w, res_b, skip_w, skip_b,
                                                w1f, w2f, wsf, hb, rb, sbt);
    prep_cond<<<dim3(NTILE, BATCH), 256, 0, stream>>>(cond, condc);
    prep_x<<<dim3(ATILE, BATCH), 256, 0, stream>>>(x, xsA, xsB, xbfA, xbfB);

    static const int dil[NLAYER] = {1, 2, 4, 8, 16, 32, 64, 128, 256, 512,
                                    1, 2, 4, 8, 16, 32, 64, 128, 256, 512};

    const float* cur = xsA; float* nxt = xsB;
    const unsigned short* bcur = xbfA; unsigned short* bnxt = xbfB;
    int l = 0, group = 0;
    while (l < NLAYER) {
        int Gc = (NLAYER - l < G) ? (NLAYER - l) : G;
        int l0 = l;
        for (int i = 0; i < Gc; ++i, ++l) {
            wavenet_mfma<<<dim3(NTILE, BATCH), 256, 0, stream>>>(
                cur, nxt, bcur, bnxt, condc,
                zg + (size_t)i * BATCH * NTILE * CELL,
                w1f, w2f, hb, rb, l, dil[l]);
            const float* t1 = nxt; nxt = (float*)cur; cur = t1;
            const unsigned short* t2 = bnxt; bnxt = (unsigned short*)bcur; bcur = t2;
        }
        skip_gemm<<<dim3(NTILE, BATCH), 256, 0, stream>>>(
            zg, wsf + (size_t)l0 * 2 * 8 * 512, sbt, out,
            2 * Gc, group == 0 ? 1 : 0, group == 0 ? 0 : 1);
        ++group;
    }
}